// Round 2
// baseline (478.816 us; speedup 1.0000x reference)
//
#include <hip/hip_runtime.h>

#define B_ 16
#define H_ 384
#define W_ 384
#define C_ 32   // floats per pixel; 8 float4 per pixel

// Grid: x = W*8/256 = 12 blocks of 256 threads (covers w * c4), y = H, z = B.
__global__ __launch_bounds__(256) void st_bilinear_kernel(
    const float* __restrict__ images,
    const float* __restrict__ theta,
    float* __restrict__ out)
{
    const int t  = blockIdx.x * 256 + threadIdx.x; // 0 .. W*8-1
    const int c4 = t & 7;                           // which float4 of the 32 channels
    const int w  = t >> 3;                          // column
    const int h  = blockIdx.y;                      // row
    const int b  = blockIdx.z;                      // batch

    // ---- adjusted theta in FP64 (b is wave-uniform -> scalar loads) ----
    const float* th = theta + b * 6;
    const double t0 = (double)th[0], t1 = (double)th[1], t2 = (double)th[2];
    const double t3 = (double)th[3], t4 = (double)th[4], t5 = (double)th[5];
    const double inv_det = 1.0 / (t0 * t4 - t1 * t3);
    const double a00 =  t4 * inv_det;   // mul[0,0]
    const double a01 = -t1 * inv_det;   // mul[0,1]
    const double a10 = -t3 * inv_det;   // mul[1,0]
    const double a11 =  t0 * inv_det;   // mul[1,1]
    const double x_center = (0.5 - t2) * a00;
    const double y_center = (0.5 - t5) * a11;
    const double c0 = 2.0 * y_center - 1.0;  // grid channel 0 offset (-> x)
    const double c1 = 2.0 * x_center - 1.0;  // grid channel 1 offset (-> y)

    // ---- normalized coords, replicating np.linspace(-1,1,N) in f64 ----
    const double step = 2.0 / 383.0;
    const double xs = (w == W_ - 1) ? 1.0 : (double)w * step - 1.0;
    const double ys = (h == H_ - 1) ? 1.0 : (double)h * step - 1.0;

    const double gx = (a00 * xs + a01 * ys) + c0;
    const double gy = (a10 * xs + a11 * ys) + c1;

    const double x = (gx + 1.0) * ((double)W_ * 0.5);
    const double y = (gy + 1.0) * ((double)H_ * 0.5);

    // ---- bilinear indices/weights in f64 (clamp ints first, as reference) ----
    const double xf = floor(x);
    const double yf = floor(y);
    int x0 = (int)xf, y0 = (int)yf;
    int x1 = x0 + 1,  y1 = y0 + 1;
    x0 = min(max(x0, 0), W_ - 1);
    x1 = min(max(x1, 0), W_ - 1);
    y0 = min(max(y0, 0), H_ - 1);
    y1 = min(max(y1, 0), H_ - 1);
    const double x0f = (double)x0, x1f = (double)x1;
    const double y0f = (double)y0, y1f = (double)y1;
    const float wa = (float)((x1f - x) * (y1f - y));
    const float wb = (float)((x1f - x) * (y - y0f));
    const float wc = (float)((x - x0f) * (y1f - y));
    const float wd = (float)((x - x0f) * (y - y0f));

    // ---- gather 4 neighbors (each a contiguous 128B pixel; this lane's float4) ----
    const float4* img4 = (const float4*)images;
    const int pix_stride = C_ / 4;          // 8 float4 per pixel
    const int row_stride = W_ * pix_stride; // per image row
    const int base_b = b * (H_ * row_stride);
    const int r0 = base_b + y0 * row_stride;
    const int r1 = base_b + y1 * row_stride;
    const int cx0 = x0 * pix_stride + c4;
    const int cx1 = x1 * pix_stride + c4;

    const float4 ga = img4[r0 + cx0];
    const float4 gb = img4[r1 + cx0];
    const float4 gc = img4[r0 + cx1];
    const float4 gd = img4[r1 + cx1];

    float4 o;
    o.x = wa * ga.x + wb * gb.x + wc * gc.x + wd * gd.x;
    o.y = wa * ga.y + wb * gb.y + wc * gc.y + wd * gd.y;
    o.z = wa * ga.z + wb * gb.z + wc * gc.z + wd * gd.z;
    o.w = wa * ga.w + wb * gb.w + wc * gc.w + wd * gd.w;

    float4* out4 = (float4*)out;
    out4[base_b + (h * W_ + w) * pix_stride + c4] = o;
}

extern "C" void kernel_launch(void* const* d_in, const int* in_sizes, int n_in,
                              void* d_out, int out_size, void* d_ws, size_t ws_size,
                              hipStream_t stream) {
    const float* images = (const float*)d_in[0];
    const float* theta  = (const float*)d_in[1];
    float* out = (float*)d_out;

    dim3 grid(W_ * (C_ / 4) / 256, H_, B_); // (12, 384, 16)
    dim3 block(256, 1, 1);
    st_bilinear_kernel<<<grid, block, 0, stream>>>(images, theta, out);
}